// Round 1
// baseline (3439.516 us; speedup 1.0000x reference)
//
#include <hip/hip_runtime.h>
#include <math.h>

#define BB 2
#define TT 2048
#define CC 1024
#define HH 16
#define DD 64
#define INNER 1024
#define BT (BB*TT)   /* 4096 */
#define EPSF 1e-6f

// Static device scratch (fully overwritten every call; deterministic).
__device__ float g_pre[BT * INNER];
__device__ float g_q[BT * INNER];
__device__ float g_k[BT * INNER];
__device__ float g_v[BT * INNER];
__device__ float g_g[BT * INNER];
__device__ float g_beta[BT * HH];
__device__ float g_decay[BT * HH];

// ---------------------------------------------------------------------------
// C[m,n] = sum_k A[m,k] * B[n,k]   (both operands K-contiguous, "NT" GEMM)
// 64x64 tile, BK=16, 256 threads, 4x4 microtile.
// ---------------------------------------------------------------------------
__global__ __launch_bounds__(256) void sgemm_nt(const float* __restrict__ A,
                                                const float* __restrict__ Bm,
                                                float* __restrict__ Cm,
                                                int M, int N, int K) {
  __shared__ float As[16][64];
  __shared__ float Bs[16][64];
  const int tid = threadIdx.x;
  const int bm = blockIdx.y * 64;
  const int bn = blockIdx.x * 64;
  const int lr = tid >> 2;        // 0..63 : row within tile
  const int lk = (tid & 3) * 4;   // 0,4,8,12 : k within k-tile
  const int tx = tid & 15;        // 0..15 : col group
  const int ty = tid >> 4;        // 0..15 : row group
  float acc[4][4] = {};
  for (int k0 = 0; k0 < K; k0 += 16) {
    float4 av = *(const float4*)&A[(bm + lr) * K + k0 + lk];
    float4 bv = *(const float4*)&Bm[(bn + lr) * K + k0 + lk];
    __syncthreads();
    As[lk + 0][lr] = av.x; As[lk + 1][lr] = av.y;
    As[lk + 2][lr] = av.z; As[lk + 3][lr] = av.w;
    Bs[lk + 0][lr] = bv.x; Bs[lk + 1][lr] = bv.y;
    Bs[lk + 2][lr] = bv.z; Bs[lk + 3][lr] = bv.w;
    __syncthreads();
#pragma unroll
    for (int kk = 0; kk < 16; ++kk) {
      float4 a4 = *(const float4*)&As[kk][ty * 4];
      float4 b4 = *(const float4*)&Bs[kk][tx * 4];
      float ar[4] = {a4.x, a4.y, a4.z, a4.w};
      float br[4] = {b4.x, b4.y, b4.z, b4.w};
#pragma unroll
      for (int i = 0; i < 4; ++i)
#pragma unroll
        for (int j = 0; j < 4; ++j) acc[i][j] += ar[i] * br[j];
    }
  }
#pragma unroll
  for (int i = 0; i < 4; ++i) {
    int m = bm + ty * 4 + i;
    float4 r = make_float4(acc[i][0], acc[i][1], acc[i][2], acc[i][3]);
    *(float4*)&Cm[m * N + bn + tx * 4] = r;
  }
}

// ---------------------------------------------------------------------------
// Causal depthwise conv1d(K=4) + SiLU, optional per-head L2 norm over D=64.
// One block per (b,t); 256 threads; thread handles 4 consecutive channels.
// ---------------------------------------------------------------------------
__global__ __launch_bounds__(256) void conv_silu_norm(
    const float* __restrict__ pre, const float* __restrict__ cw,
    const float* __restrict__ cb, float* __restrict__ out, int do_l2) {
  const int bt = blockIdx.x;
  const int b = bt / TT, t = bt % TT;
  const int tid = threadIdx.x;
  const int c4 = tid * 4;
  float4 xt[4];
#pragma unroll
  for (int j = 0; j < 4; ++j) {
    int ts = t - 3 + j;
    xt[j] = (ts >= 0) ? *(const float4*)&pre[(b * TT + ts) * INNER + c4]
                      : make_float4(0.f, 0.f, 0.f, 0.f);
  }
  float4 bias4 = *(const float4*)&cb[c4];
  const float* bp = (const float*)&bias4;
  float y[4];
#pragma unroll
  for (int ci = 0; ci < 4; ++ci) {
    float4 w4 = *(const float4*)&cw[(c4 + ci) * 4];
    float acc = bp[ci];
    acc += w4.x * ((const float*)&xt[0])[ci];
    acc += w4.y * ((const float*)&xt[1])[ci];
    acc += w4.z * ((const float*)&xt[2])[ci];
    acc += w4.w * ((const float*)&xt[3])[ci];
    y[ci] = acc / (1.f + expf(-acc));   // SiLU
  }
  if (do_l2) {
    float ssq = y[0]*y[0] + y[1]*y[1] + y[2]*y[2] + y[3]*y[3];
    ssq += __shfl_xor(ssq, 1);
    ssq += __shfl_xor(ssq, 2);
    ssq += __shfl_xor(ssq, 4);
    ssq += __shfl_xor(ssq, 8);   // 16 threads = one head (64 channels)
    float r = rsqrtf(ssq + EPSF);
    y[0] *= r; y[1] *= r; y[2] *= r; y[3] *= r;
  }
  *(float4*)&out[bt * INNER + c4] = make_float4(y[0], y[1], y[2], y[3]);
}

// ---------------------------------------------------------------------------
// beta = sigmoid(x@wb.T); decay = exp(-exp(A_log)*softplus(x@wa.T + dt_bias))
// One block (64 threads) per (b,t) row; lanes 0..15 -> wa, 16..31 -> wb.
// ---------------------------------------------------------------------------
__global__ __launch_bounds__(64) void proj_ab(
    const float* __restrict__ x, const float* __restrict__ wa,
    const float* __restrict__ wb, const float* __restrict__ dt_bias,
    const float* __restrict__ A_log, float* __restrict__ beta,
    float* __restrict__ decay) {
  const int m = blockIdx.x;
  const int lane = threadIdx.x;
  const float* xr = &x[m * CC];
  if (lane < 16) {
    const float* wr = &wa[lane * CC];
    float acc = 0.f;
    for (int kk = 0; kk < CC; kk += 4) {
      float4 xv = *(const float4*)&xr[kk];
      float4 wv = *(const float4*)&wr[kk];
      acc += xv.x * wv.x + xv.y * wv.y + xv.z * wv.z + xv.w * wv.w;
    }
    float a = acc + dt_bias[lane];
    float sp = fmaxf(a, 0.f) + log1pf(expf(-fabsf(a)));  // softplus, stable
    decay[m * HH + lane] = expf(-expf(A_log[lane]) * sp);
  } else if (lane < 32) {
    const int hh = lane - 16;
    const float* wr = &wb[hh * CC];
    float acc = 0.f;
    for (int kk = 0; kk < CC; kk += 4) {
      float4 xv = *(const float4*)&xr[kk];
      float4 wv = *(const float4*)&wr[kk];
      acc += xv.x * wv.x + xv.y * wv.y + xv.z * wv.z + xv.w * wv.w;
    }
    beta[m * HH + hh] = 1.f / (1.f + expf(-acc));
  }
}

// ---------------------------------------------------------------------------
// Sequential delta-rule scan. One wave (64 lanes) per (b,h); lane = e column.
// S[d][e] lives in 64 VGPRs of lane e. q/k/v staged in LDS per 64-step chunk.
// ---------------------------------------------------------------------------
#define SCHUNK 64
__global__ __launch_bounds__(64) void scan_kernel(
    const float* __restrict__ q, const float* __restrict__ k,
    const float* __restrict__ v, const float* __restrict__ beta,
    const float* __restrict__ decay, float* __restrict__ o) {
  const int bh = blockIdx.x;
  const int b = bh >> 4, h = bh & 15;
  const int lane = threadIdx.x;
  __shared__ float qs[SCHUNK][64];
  __shared__ float ks[SCHUNK][64];
  __shared__ float vs[SCHUNK][64];
  __shared__ float bs[SCHUNK];
  __shared__ float ds_[SCHUNK];
  float S[64];
#pragma unroll
  for (int i = 0; i < 64; ++i) S[i] = 0.f;

  for (int c0 = 0; c0 < TT; c0 += SCHUNK) {
    __syncthreads();
    // stage chunk: 64 steps x 64 dims, coalesced float4 loads
#pragma unroll 4
    for (int it = 0; it < 16; ++it) {
      int tt = it * 4 + (lane >> 4);
      int d4 = (lane & 15) * 4;
      int gbase = ((b * TT + c0 + tt) * HH + h) * DD + d4;
      *(float4*)&qs[tt][d4] = *(const float4*)&q[gbase];
      *(float4*)&ks[tt][d4] = *(const float4*)&k[gbase];
      *(float4*)&vs[tt][d4] = *(const float4*)&v[gbase];
    }
    {
      int idx = (b * TT + c0 + lane) * HH + h;
      bs[lane] = beta[idx];
      ds_[lane] = decay[idx];
    }
    __syncthreads();

    for (int tt = 0; tt < SCHUNK; ++tt) {
      const float4* krow = (const float4*)&ks[tt][0];
      const float4* qrow = (const float4*)&qs[tt][0];
      // phase 1: kS[e] = sum_d k[d] * S[d][e]
      float kS0 = 0.f, kS1 = 0.f, kS2 = 0.f, kS3 = 0.f;
#pragma unroll
      for (int d4 = 0; d4 < 16; ++d4) {
        float4 kk4 = krow[d4];
        kS0 += kk4.x * S[d4 * 4 + 0];
        kS1 += kk4.y * S[d4 * 4 + 1];
        kS2 += kk4.z * S[d4 * 4 + 2];
        kS3 += kk4.w * S[d4 * 4 + 3];
      }
      float kS = (kS0 + kS1) + (kS2 + kS3);
      float w = bs[tt] * (vs[tt][lane] - kS);   // beta * delta[e]
      float dec = ds_[tt];
      // phase 2: S[d][e] = dec*S + k[d]*w ; o[e] += q[d]*S_new
      float o0 = 0.f, o1 = 0.f, o2 = 0.f, o3 = 0.f;
#pragma unroll
      for (int d4 = 0; d4 < 16; ++d4) {
        float4 kk4 = krow[d4];
        float4 qq4 = qrow[d4];
        float s;
        s = dec * S[d4*4+0] + kk4.x * w; S[d4*4+0] = s; o0 += qq4.x * s;
        s = dec * S[d4*4+1] + kk4.y * w; S[d4*4+1] = s; o1 += qq4.y * s;
        s = dec * S[d4*4+2] + kk4.z * w; S[d4*4+2] = s; o2 += qq4.z * s;
        s = dec * S[d4*4+3] + kk4.w * w; S[d4*4+3] = s; o3 += qq4.w * s;
      }
      o[((b * TT + c0 + tt) * HH + h) * DD + lane] = (o0 + o1) + (o2 + o3);
    }
  }
}

// ---------------------------------------------------------------------------
// o = rms_norm(o) * o_norm_scale * silu(g);  per (b,t), per-head RMS over D.
// ---------------------------------------------------------------------------
__global__ __launch_bounds__(256) void norm_gate(
    const float* __restrict__ o, const float* __restrict__ g,
    const float* __restrict__ scale, float* __restrict__ out) {
  const int bt = blockIdx.x;
  const int tid = threadIdx.x;
  const int c4 = tid * 4;
  float4 o4 = *(const float4*)&o[bt * INNER + c4];
  float ssq = o4.x*o4.x + o4.y*o4.y + o4.z*o4.z + o4.w*o4.w;
  ssq += __shfl_xor(ssq, 1);
  ssq += __shfl_xor(ssq, 2);
  ssq += __shfl_xor(ssq, 4);
  ssq += __shfl_xor(ssq, 8);
  float r = rsqrtf(ssq * (1.f / 64.f) + EPSF);
  float4 sc = *(const float4*)&scale[c4 & 63];
  float4 g4 = *(const float4*)&g[bt * INNER + c4];
  float4 res;
  res.x = o4.x * r * sc.x * (g4.x / (1.f + expf(-g4.x)));
  res.y = o4.y * r * sc.y * (g4.y / (1.f + expf(-g4.y)));
  res.z = o4.z * r * sc.z * (g4.z / (1.f + expf(-g4.z)));
  res.w = o4.w * r * sc.w * (g4.w / (1.f + expf(-g4.w)));
  *(float4*)&out[bt * INNER + c4] = res;
}

// ---------------------------------------------------------------------------
extern "C" void kernel_launch(void* const* d_in, const int* in_sizes, int n_in,
                              void* d_out, int out_size, void* d_ws,
                              size_t ws_size, hipStream_t stream) {
  const float* x      = (const float*)d_in[0];
  const float* wq     = (const float*)d_in[1];
  const float* wk     = (const float*)d_in[2];
  const float* wv     = (const float*)d_in[3];
  const float* wg     = (const float*)d_in[4];
  const float* wo     = (const float*)d_in[5];
  const float* wa     = (const float*)d_in[6];
  const float* wb     = (const float*)d_in[7];
  const float* cqw    = (const float*)d_in[8];
  const float* cqb    = (const float*)d_in[9];
  const float* ckw    = (const float*)d_in[10];
  const float* ckb    = (const float*)d_in[11];
  const float* cvw    = (const float*)d_in[12];
  const float* cvb    = (const float*)d_in[13];
  const float* A_log  = (const float*)d_in[14];
  const float* dtb    = (const float*)d_in[15];
  const float* oscale = (const float*)d_in[16];
  float* out = (float*)d_out;

  float *pre, *q, *k, *v, *g, *beta, *decay;
  hipGetSymbolAddress((void**)&pre,   HIP_SYMBOL(g_pre));
  hipGetSymbolAddress((void**)&q,     HIP_SYMBOL(g_q));
  hipGetSymbolAddress((void**)&k,     HIP_SYMBOL(g_k));
  hipGetSymbolAddress((void**)&v,     HIP_SYMBOL(g_v));
  hipGetSymbolAddress((void**)&g,     HIP_SYMBOL(g_g));
  hipGetSymbolAddress((void**)&beta,  HIP_SYMBOL(g_beta));
  hipGetSymbolAddress((void**)&decay, HIP_SYMBOL(g_decay));

  dim3 ggrid(INNER / 64, BT / 64);   // (16, 64)
  dim3 gblk(256);

  // q projection -> conv+silu+l2
  sgemm_nt<<<ggrid, gblk, 0, stream>>>(x, wq, pre, BT, INNER, CC);
  conv_silu_norm<<<BT, 256, 0, stream>>>(pre, cqw, cqb, q, 1);
  // k
  sgemm_nt<<<ggrid, gblk, 0, stream>>>(x, wk, pre, BT, INNER, CC);
  conv_silu_norm<<<BT, 256, 0, stream>>>(pre, ckw, ckb, k, 1);
  // v (no norm)
  sgemm_nt<<<ggrid, gblk, 0, stream>>>(x, wv, pre, BT, INNER, CC);
  conv_silu_norm<<<BT, 256, 0, stream>>>(pre, cvw, cvb, v, 0);
  // g (raw projection)
  sgemm_nt<<<ggrid, gblk, 0, stream>>>(x, wg, g, BT, INNER, CC);
  // beta / decay
  proj_ab<<<BT, 64, 0, stream>>>(x, wa, wb, dtb, A_log, beta, decay);
  // sequential delta-rule scan -> o (stored in d_out as scratch)
  scan_kernel<<<BB * HH, 64, 0, stream>>>(q, k, v, beta, decay, out);
  // rms-norm * scale * silu(g) -> gated (reuse pre)
  norm_gate<<<BT, 256, 0, stream>>>(out, g, oscale, pre);
  // final projection: out = gated @ wo.T
  sgemm_nt<<<ggrid, gblk, 0, stream>>>(pre, wo, out, BT, CC, INNER);
}

// Round 2
// 1191.191 us; speedup vs baseline: 2.8875x; 2.8875x over previous
//
#include <hip/hip_runtime.h>
#include <math.h>

#define BB 2
#define TT 2048
#define CC 1024
#define HH 16
#define DD 64
#define INNER 1024
#define BT (BB*TT)   /* 4096 */
#define EPSF 1e-6f
#define CH 64
#define NC (TT/CH)        /* 32 */
#define NBH (BB*HH)       /* 32 */
#define NCHK (NBH*NC)     /* 1024 */

// Static device scratch (fully overwritten every call; deterministic).
__device__ float g_pre[BT * INNER];
__device__ float g_q[BT * INNER];
__device__ float g_k[BT * INNER];
__device__ float g_v[BT * INNER];
__device__ float g_g[BT * INNER];
__device__ float g_beta[BT * HH];
__device__ float g_ldec[BT * HH];
// per-chunk precomputed tensors
__device__ float g_U0[NCHK * CH * DD];
__device__ float g_Wt[NCHK * DD * CH];
__device__ float g_Bt[NCHK * CH * CH];
__device__ float g_Qht[NCHK * DD * CH];
__device__ float g_Kh[NCHK * CH * DD];
__device__ float g_gL[NCHK];

// ---------------------------------------------------------------------------
// C[m,n] = sum_k A[m,k] * B[n,k]   (both operands K-contiguous, "NT" GEMM)
// ---------------------------------------------------------------------------
__global__ __launch_bounds__(256) void sgemm_nt(const float* __restrict__ A,
                                                const float* __restrict__ Bm,
                                                float* __restrict__ Cm,
                                                int M, int N, int K) {
  __shared__ float As[16][64];
  __shared__ float Bs[16][64];
  const int tid = threadIdx.x;
  const int bm = blockIdx.y * 64;
  const int bn = blockIdx.x * 64;
  const int lr = tid >> 2;
  const int lk = (tid & 3) * 4;
  const int tx = tid & 15;
  const int ty = tid >> 4;
  float acc[4][4] = {};
  for (int k0 = 0; k0 < K; k0 += 16) {
    float4 av = *(const float4*)&A[(bm + lr) * K + k0 + lk];
    float4 bv = *(const float4*)&Bm[(bn + lr) * K + k0 + lk];
    __syncthreads();
    As[lk + 0][lr] = av.x; As[lk + 1][lr] = av.y;
    As[lk + 2][lr] = av.z; As[lk + 3][lr] = av.w;
    Bs[lk + 0][lr] = bv.x; Bs[lk + 1][lr] = bv.y;
    Bs[lk + 2][lr] = bv.z; Bs[lk + 3][lr] = bv.w;
    __syncthreads();
#pragma unroll
    for (int kk = 0; kk < 16; ++kk) {
      float4 a4 = *(const float4*)&As[kk][ty * 4];
      float4 b4 = *(const float4*)&Bs[kk][tx * 4];
      float ar[4] = {a4.x, a4.y, a4.z, a4.w};
      float br[4] = {b4.x, b4.y, b4.z, b4.w};
#pragma unroll
      for (int i = 0; i < 4; ++i)
#pragma unroll
        for (int j = 0; j < 4; ++j) acc[i][j] += ar[i] * br[j];
    }
  }
#pragma unroll
  for (int i = 0; i < 4; ++i) {
    int m = bm + ty * 4 + i;
    float4 r = make_float4(acc[i][0], acc[i][1], acc[i][2], acc[i][3]);
    *(float4*)&Cm[m * N + bn + tx * 4] = r;
  }
}

// ---------------------------------------------------------------------------
// Causal depthwise conv1d(K=4) + SiLU, optional per-head L2 norm over D=64.
// ---------------------------------------------------------------------------
__global__ __launch_bounds__(256) void conv_silu_norm(
    const float* __restrict__ pre, const float* __restrict__ cw,
    const float* __restrict__ cb, float* __restrict__ out, int do_l2) {
  const int bt = blockIdx.x;
  const int b = bt / TT, t = bt % TT;
  const int tid = threadIdx.x;
  const int c4 = tid * 4;
  float4 xt[4];
#pragma unroll
  for (int j = 0; j < 4; ++j) {
    int ts = t - 3 + j;
    xt[j] = (ts >= 0) ? *(const float4*)&pre[(b * TT + ts) * INNER + c4]
                      : make_float4(0.f, 0.f, 0.f, 0.f);
  }
  float4 bias4 = *(const float4*)&cb[c4];
  const float* bp = (const float*)&bias4;
  float y[4];
#pragma unroll
  for (int ci = 0; ci < 4; ++ci) {
    float4 w4 = *(const float4*)&cw[(c4 + ci) * 4];
    float acc = bp[ci];
    acc += w4.x * ((const float*)&xt[0])[ci];
    acc += w4.y * ((const float*)&xt[1])[ci];
    acc += w4.z * ((const float*)&xt[2])[ci];
    acc += w4.w * ((const float*)&xt[3])[ci];
    y[ci] = acc / (1.f + expf(-acc));   // SiLU
  }
  if (do_l2) {
    float ssq = y[0]*y[0] + y[1]*y[1] + y[2]*y[2] + y[3]*y[3];
    ssq += __shfl_xor(ssq, 1);
    ssq += __shfl_xor(ssq, 2);
    ssq += __shfl_xor(ssq, 4);
    ssq += __shfl_xor(ssq, 8);
    float r = rsqrtf(ssq + EPSF);
    y[0] *= r; y[1] *= r; y[2] *= r; y[3] *= r;
  }
  *(float4*)&out[bt * INNER + c4] = make_float4(y[0], y[1], y[2], y[3]);
}

// ---------------------------------------------------------------------------
// beta = sigmoid(x@wb.T); ldec = -exp(A_log)*softplus(x@wa.T + dt_bias)
// ---------------------------------------------------------------------------
__global__ __launch_bounds__(64) void proj_ab(
    const float* __restrict__ x, const float* __restrict__ wa,
    const float* __restrict__ wb, const float* __restrict__ dt_bias,
    const float* __restrict__ A_log, float* __restrict__ beta,
    float* __restrict__ ldec) {
  const int m = blockIdx.x;
  const int lane = threadIdx.x;
  const float* xr = &x[m * CC];
  if (lane < 16) {
    const float* wr = &wa[lane * CC];
    float acc = 0.f;
    for (int kk = 0; kk < CC; kk += 4) {
      float4 xv = *(const float4*)&xr[kk];
      float4 wv = *(const float4*)&wr[kk];
      acc += xv.x * wv.x + xv.y * wv.y + xv.z * wv.z + xv.w * wv.w;
    }
    float a = acc + dt_bias[lane];
    float sp = fmaxf(a, 0.f) + log1pf(expf(-fabsf(a)));  // softplus, stable
    ldec[m * HH + lane] = -expf(A_log[lane]) * sp;       // log of decay
  } else if (lane < 32) {
    const int hh = lane - 16;
    const float* wr = &wb[hh * CC];
    float acc = 0.f;
    for (int kk = 0; kk < CC; kk += 4) {
      float4 xv = *(const float4*)&xr[kk];
      float4 wv = *(const float4*)&wr[kk];
      acc += xv.x * wv.x + xv.y * wv.y + xv.z * wv.z + xv.w * wv.w;
    }
    beta[m * HH + hh] = 1.f / (1.f + expf(-acc));
  }
}

// ---------------------------------------------------------------------------
// Per-chunk parallel precompute for chunked delta rule.
// grid = NBH*NC blocks (1024), 256 threads.
// Produces U0, Wt (transposed), Bt (transposed), Qht (transposed), Kh, gL.
// ---------------------------------------------------------------------------
__global__ __launch_bounds__(256) void gdn_prep(
    const float* __restrict__ q, const float* __restrict__ k,
    const float* __restrict__ v, const float* __restrict__ beta,
    const float* __restrict__ ldec,
    float* __restrict__ U0g, float* __restrict__ Wtg, float* __restrict__ Btg,
    float* __restrict__ Qhtg, float* __restrict__ Khg, float* __restrict__ gLg) {
  const int blk = blockIdx.x;
  const int bh = blk / NC, c = blk % NC;
  const int b = bh >> 4, h = bh & 15;
  const int tid = threadIdx.x;
  const int tx = tid & 15, ty = tid >> 4;
  __shared__ float P0[64][68];   // kst[d][t] -> later U0[t][e]
  __shared__ float P1[64][68];   // qst[d][t] -> later W[t][d]
  __shared__ float Ab[64][65];   // A[t][s]
  __shared__ float lam[64], lamx[64], lbet[64];
  const long gb = ((long)(b * TT + c * CH) * HH + h) * DD;

  // stage k,q transposed
  {
    const int e4 = (tid & 15) * 4;
    const int t0 = tid >> 4;
#pragma unroll
    for (int p = 0; p < 4; ++p) {
      int t = t0 + p * 16;
      float4 kv = *(const float4*)&k[gb + (long)t * (HH * DD) + e4];
      float4 qv = *(const float4*)&q[gb + (long)t * (HH * DD) + e4];
      P0[e4 + 0][t] = kv.x; P0[e4 + 1][t] = kv.y;
      P0[e4 + 2][t] = kv.z; P0[e4 + 3][t] = kv.w;
      P1[e4 + 0][t] = qv.x; P1[e4 + 1][t] = qv.y;
      P1[e4 + 2][t] = qv.z; P1[e4 + 3][t] = qv.w;
    }
  }
  // lam (inclusive log-decay prefix), lamx (exclusive), lbet
  float ldv = 0.f, bv_ = 0.f;
  if (tid < 64) {
    ldv = ldec[(long)(b * TT + c * CH + tid) * HH + h];
    bv_ = beta[(long)(b * TT + c * CH + tid) * HH + h];
    lam[tid] = ldv;
  }
  __syncthreads();
  float lsum = 0.f;
  if (tid < 64) {
    for (int s = 0; s <= tid; ++s) lsum += lam[s];
  }
  __syncthreads();
  if (tid < 64) {
    lam[tid] = lsum;
    lamx[tid] = lsum - ldv;
    lbet[tid] = bv_;
  }
  __syncthreads();

  // G[r][c]=k_r.k_c ; Pm[r][c]=k_r.q_c  (both via transposed operands)
  float accg[4][4] = {}, accp[4][4] = {};
  for (int d = 0; d < 64; ++d) {
    float4 a4 = *(const float4*)&P0[d][ty * 4];
    float4 bk = *(const float4*)&P0[d][tx * 4];
    float4 bq = *(const float4*)&P1[d][tx * 4];
    float ar[4] = {a4.x, a4.y, a4.z, a4.w};
    float bkr[4] = {bk.x, bk.y, bk.z, bk.w};
    float bqr[4] = {bq.x, bq.y, bq.z, bq.w};
#pragma unroll
    for (int i = 0; i < 4; ++i)
#pragma unroll
      for (int j = 0; j < 4; ++j) {
        accg[i][j] += ar[i] * bkr[j];
        accp[i][j] += ar[i] * bqr[j];
      }
  }
  // A[t][s] = (s<t) beta_t exp(lamx_t - lam_s) k_t.k_s   (t=ty4+i rows of accg)
#pragma unroll
  for (int i = 0; i < 4; ++i) {
    int t = ty * 4 + i;
    float bt_ = lbet[t], lx = lamx[t];
#pragma unroll
    for (int j = 0; j < 4; ++j) {
      int s = tx * 4 + j;
      Ab[t][s] = (s < t) ? bt_ * expf(lx - lam[s]) * accg[i][j] : 0.f;
    }
  }
  // Bt[s][t] = (s<=t) exp(lam_t - lam_s) q_t.k_s   (s=ty4+i, t=tx4+j)
  {
    float* btp = Btg + (long)blk * (CH * CH);
#pragma unroll
    for (int i = 0; i < 4; ++i) {
      int s = ty * 4 + i;
      float ls = lam[s];
      int t0 = tx * 4;
      float4 w;
      w.x = (s <= t0 + 0) ? expf(lam[t0 + 0] - ls) * accp[i][0] : 0.f;
      w.y = (s <= t0 + 1) ? expf(lam[t0 + 1] - ls) * accp[i][1] : 0.f;
      w.z = (s <= t0 + 2) ? expf(lam[t0 + 2] - ls) * accp[i][2] : 0.f;
      w.w = (s <= t0 + 3) ? expf(lam[t0 + 3] - ls) * accp[i][3] : 0.f;
      *(float4*)&btp[s * 64 + t0] = w;
    }
  }
  // Qht[d][t] = exp(lam_t) q[t][d]  (from qst, before P1 is reused)
  {
    float* qhp = Qhtg + (long)blk * (DD * CH);
    const int t4 = (tid & 15) * 4;
    const int d0 = tid >> 4;
#pragma unroll
    for (int p = 0; p < 4; ++p) {
      int d = d0 + p * 16;
      float4 qv = *(const float4*)&P1[d][t4];
      qv.x *= expf(lam[t4 + 0]); qv.y *= expf(lam[t4 + 1]);
      qv.z *= expf(lam[t4 + 2]); qv.w *= expf(lam[t4 + 3]);
      *(float4*)&qhp[d * 64 + t4] = qv;
    }
  }
  __syncthreads();
  // re-init: P0[t][e] = beta_t v ; P1[t][d] = beta_t exp(lamx_t) k
  {
    const int e4 = (tid & 15) * 4;
    const int t0 = tid >> 4;
#pragma unroll
    for (int p = 0; p < 4; ++p) {
      int t = t0 + p * 16;
      float bt_ = lbet[t], cx = bt_ * expf(lamx[t]);
      float4 vv = *(const float4*)&v[gb + (long)t * (HH * DD) + e4];
      float4 kv = *(const float4*)&k[gb + (long)t * (HH * DD) + e4];
      vv.x *= bt_; vv.y *= bt_; vv.z *= bt_; vv.w *= bt_;
      kv.x *= cx; kv.y *= cx; kv.z *= cx; kv.w *= cx;
      *(float4*)&P0[t][e4] = vv;
      *(float4*)&P1[t][e4] = kv;
    }
  }
  __syncthreads();
  // forward substitution (right-looking): rows r>t -= A[r][t]*row t, both P0,P1
  {
    const int j4 = (tid & 31) * 4;  // 0..124 ; <64 -> P0 col, else P1 col
    const int rofs = tid >> 5;      // 0..7
    float* Pj = (j4 < 64) ? (&P0[0][0] + j4) : (&P1[0][0] + (j4 - 64));
    for (int t = 0; t < 63; ++t) {
      __syncthreads();
      float4 ut = *(const float4*)&Pj[t * 68];
      for (int r = t + 1 + rofs; r < 64; r += 8) {
        float a = Ab[r][t];
        float4 ur = *(const float4*)&Pj[r * 68];
        ur.x -= a * ut.x; ur.y -= a * ut.y;
        ur.z -= a * ut.z; ur.w -= a * ut.w;
        *(float4*)&Pj[r * 68] = ur;
      }
    }
  }
  __syncthreads();
  // write U0 (natural) and Wt (transposed)
  {
    float* u0p = U0g + (long)blk * (CH * DD);
    const int e4 = (tid & 15) * 4;
    const int t0 = tid >> 4;
#pragma unroll
    for (int p = 0; p < 4; ++p) {
      int t = t0 + p * 16;
      *(float4*)&u0p[t * 64 + e4] = *(const float4*)&P0[t][e4];
    }
    float* wtp = Wtg + (long)blk * (DD * CH);
    const int t = tid & 63;
    const int d0 = tid >> 6;  // 0..3
#pragma unroll
    for (int p = 0; p < 16; ++p) {
      int d = d0 + p * 4;
      wtp[d * 64 + t] = P1[t][d];
    }
  }
  // Kh[s][d] = exp(lamL - lam_s) k[s][d] ; gL
  {
    float* khp = Khg + (long)blk * (CH * DD);
    float lamL = lam[63];
    const int e4 = (tid & 15) * 4;
    const int t0 = tid >> 4;
#pragma unroll
    for (int p = 0; p < 4; ++p) {
      int t = t0 + p * 16;
      float cf = expf(lamL - lam[t]);
      float4 kv = *(const float4*)&k[gb + (long)t * (HH * DD) + e4];
      kv.x *= cf; kv.y *= cf; kv.z *= cf; kv.w *= cf;
      *(float4*)&khp[t * 64 + e4] = kv;
    }
    if (tid == 0) gLg[blk] = expf(lamL);
  }
}

// ---------------------------------------------------------------------------
// Sequential inter-chunk pass: per (b,h), 32 chunk steps of 64x64x64 matmuls.
// u = U0 - W.S ; o = B.u + Qh.S ; S = gL.S + Kh^T.u
// ---------------------------------------------------------------------------
__global__ __launch_bounds__(256) void gdn_seq(
    const float* __restrict__ U0g, const float* __restrict__ Wtg,
    const float* __restrict__ Btg, const float* __restrict__ Qhtg,
    const float* __restrict__ Khg, const float* __restrict__ gLg,
    float* __restrict__ o) {
  const int bh = blockIdx.x;
  const int b = bh >> 4, h = bh & 15;
  const int tid = threadIdx.x;
  const int tx = tid & 15, ty = tid >> 4;
  __shared__ float S[64][64];
  __shared__ float ub[64][64];
  __shared__ float op[64][64];
#pragma unroll
  for (int p = 0; p < 16; ++p) ((float*)S)[tid + p * 256] = 0.f;
  const int e4 = (tid & 15) * 4;
  const int t0s = tid >> 4;

  for (int c = 0; c < NC; ++c) {
    const long blk = (long)(bh * NC + c);
    const float* wt = Wtg + blk * (DD * CH);
    const float* u0 = U0g + blk * (CH * DD);
    const float* bt = Btg + blk * (CH * CH);
    const float* qh = Qhtg + blk * (DD * CH);
    const float* kh = Khg + blk * (CH * DD);
    __syncthreads();
    // stage Wt
#pragma unroll
    for (int p = 0; p < 4; ++p) {
      int t = t0s + p * 16;
      *(float4*)&op[t][e4] = *(const float4*)&wt[t * 64 + e4];
    }
    __syncthreads();
    // u = U0 - W.S
    float acc[4][4];
#pragma unroll
    for (int i = 0; i < 4; ++i) {
      float4 u4 = *(const float4*)&u0[(ty * 4 + i) * 64 + tx * 4];
      acc[i][0] = u4.x; acc[i][1] = u4.y; acc[i][2] = u4.z; acc[i][3] = u4.w;
    }
    for (int d = 0; d < 64; ++d) {
      float4 a4 = *(const float4*)&op[d][ty * 4];
      float4 b4 = *(const float4*)&S[d][tx * 4];
      float ar[4] = {a4.x, a4.y, a4.z, a4.w};
      float br[4] = {b4.x, b4.y, b4.z, b4.w};
#pragma unroll
      for (int i = 0; i < 4; ++i)
#pragma unroll
        for (int j = 0; j < 4; ++j) acc[i][j] -= ar[i] * br[j];
    }
#pragma unroll
    for (int i = 0; i < 4; ++i)
      *(float4*)&ub[ty * 4 + i][tx * 4] =
          make_float4(acc[i][0], acc[i][1], acc[i][2], acc[i][3]);
    __syncthreads();
    // stage Bt
#pragma unroll
    for (int p = 0; p < 4; ++p) {
      int t = t0s + p * 16;
      *(float4*)&op[t][e4] = *(const float4*)&bt[t * 64 + e4];
    }
    __syncthreads();
    // o part1 = B.u
    float acco[4][4] = {};
    for (int s = 0; s < 64; ++s) {
      float4 a4 = *(const float4*)&op[s][ty * 4];
      float4 b4 = *(const float4*)&ub[s][tx * 4];
      float ar[4] = {a4.x, a4.y, a4.z, a4.w};
      float br[4] = {b4.x, b4.y, b4.z, b4.w};
#pragma unroll
      for (int i = 0; i < 4; ++i)
#pragma unroll
        for (int j = 0; j < 4; ++j) acco[i][j] += ar[i] * br[j];
    }
    __syncthreads();
    // stage Qht
#pragma unroll
    for (int p = 0; p < 4; ++p) {
      int t = t0s + p * 16;
      *(float4*)&op[t][e4] = *(const float4*)&qh[t * 64 + e4];
    }
    __syncthreads();
    // o part2 += Qh.S ; write o
    for (int d = 0; d < 64; ++d) {
      float4 a4 = *(const float4*)&op[d][ty * 4];
      float4 b4 = *(const float4*)&S[d][tx * 4];
      float ar[4] = {a4.x, a4.y, a4.z, a4.w};
      float br[4] = {b4.x, b4.y, b4.z, b4.w};
#pragma unroll
      for (int i = 0; i < 4; ++i)
#pragma unroll
        for (int j = 0; j < 4; ++j) acco[i][j] += ar[i] * br[j];
    }
#pragma unroll
    for (int i = 0; i < 4; ++i) {
      int t = ty * 4 + i;
      *(float4*)&o[((long)(b * TT + c * CH + t) * HH + h) * DD + tx * 4] =
          make_float4(acco[i][0], acco[i][1], acco[i][2], acco[i][3]);
    }
    __syncthreads();
    // stage Kh
#pragma unroll
    for (int p = 0; p < 4; ++p) {
      int t = t0s + p * 16;
      *(float4*)&op[t][e4] = *(const float4*)&kh[t * 64 + e4];
    }
    __syncthreads();
    // S = gL*S + Kh^T.u   (rows d = ty4+i, cols e = tx4+j)
    float gL = gLg[blk];
    float accs[4][4];
#pragma unroll
    for (int i = 0; i < 4; ++i)
#pragma unroll
      for (int j = 0; j < 4; ++j) accs[i][j] = gL * S[ty * 4 + i][tx * 4 + j];
    for (int s = 0; s < 64; ++s) {
      float4 a4 = *(const float4*)&op[s][ty * 4];
      float4 b4 = *(const float4*)&ub[s][tx * 4];
      float ar[4] = {a4.x, a4.y, a4.z, a4.w};
      float br[4] = {b4.x, b4.y, b4.z, b4.w};
#pragma unroll
      for (int i = 0; i < 4; ++i)
#pragma unroll
        for (int j = 0; j < 4; ++j) accs[i][j] += ar[i] * br[j];
    }
#pragma unroll
    for (int i = 0; i < 4; ++i)
      *(float4*)&S[ty * 4 + i][tx * 4] =
          make_float4(accs[i][0], accs[i][1], accs[i][2], accs[i][3]);
  }
}

// ---------------------------------------------------------------------------
// o = rms_norm(o) * o_norm_scale * silu(g)
// ---------------------------------------------------------------------------
__global__ __launch_bounds__(256) void norm_gate(
    const float* __restrict__ o, const float* __restrict__ g,
    const float* __restrict__ scale, float* __restrict__ out) {
  const int bt = blockIdx.x;
  const int tid = threadIdx.x;
  const int c4 = tid * 4;
  float4 o4 = *(const float4*)&o[bt * INNER + c4];
  float ssq = o4.x * o4.x + o4.y * o4.y + o4.z * o4.z + o4.w * o4.w;
  ssq += __shfl_xor(ssq, 1);
  ssq += __shfl_xor(ssq, 2);
  ssq += __shfl_xor(ssq, 4);
  ssq += __shfl_xor(ssq, 8);
  float r = rsqrtf(ssq * (1.f / 64.f) + EPSF);
  float4 sc = *(const float4*)&scale[c4 & 63];
  float4 g4 = *(const float4*)&g[bt * INNER + c4];
  float4 res;
  res.x = o4.x * r * sc.x * (g4.x / (1.f + expf(-g4.x)));
  res.y = o4.y * r * sc.y * (g4.y / (1.f + expf(-g4.y)));
  res.z = o4.z * r * sc.z * (g4.z / (1.f + expf(-g4.z)));
  res.w = o4.w * r * sc.w * (g4.w / (1.f + expf(-g4.w)));
  *(float4*)&out[bt * INNER + c4] = res;
}

// ---------------------------------------------------------------------------
extern "C" void kernel_launch(void* const* d_in, const int* in_sizes, int n_in,
                              void* d_out, int out_size, void* d_ws,
                              size_t ws_size, hipStream_t stream) {
  const float* x      = (const float*)d_in[0];
  const float* wq     = (const float*)d_in[1];
  const float* wk     = (const float*)d_in[2];
  const float* wv     = (const float*)d_in[3];
  const float* wg     = (const float*)d_in[4];
  const float* wo     = (const float*)d_in[5];
  const float* wa     = (const float*)d_in[6];
  const float* wb     = (const float*)d_in[7];
  const float* cqw    = (const float*)d_in[8];
  const float* cqb    = (const float*)d_in[9];
  const float* ckw    = (const float*)d_in[10];
  const float* ckb    = (const float*)d_in[11];
  const float* cvw    = (const float*)d_in[12];
  const float* cvb    = (const float*)d_in[13];
  const float* A_log  = (const float*)d_in[14];
  const float* dtb    = (const float*)d_in[15];
  const float* oscale = (const float*)d_in[16];
  float* out = (float*)d_out;

  float *pre, *q, *k, *v, *g, *beta, *ldec;
  float *U0, *Wt, *Bt, *Qht, *Kh, *gL;
  hipGetSymbolAddress((void**)&pre,  HIP_SYMBOL(g_pre));
  hipGetSymbolAddress((void**)&q,    HIP_SYMBOL(g_q));
  hipGetSymbolAddress((void**)&k,    HIP_SYMBOL(g_k));
  hipGetSymbolAddress((void**)&v,    HIP_SYMBOL(g_v));
  hipGetSymbolAddress((void**)&g,    HIP_SYMBOL(g_g));
  hipGetSymbolAddress((void**)&beta, HIP_SYMBOL(g_beta));
  hipGetSymbolAddress((void**)&ldec, HIP_SYMBOL(g_ldec));
  hipGetSymbolAddress((void**)&U0,   HIP_SYMBOL(g_U0));
  hipGetSymbolAddress((void**)&Wt,   HIP_SYMBOL(g_Wt));
  hipGetSymbolAddress((void**)&Bt,   HIP_SYMBOL(g_Bt));
  hipGetSymbolAddress((void**)&Qht,  HIP_SYMBOL(g_Qht));
  hipGetSymbolAddress((void**)&Kh,   HIP_SYMBOL(g_Kh));
  hipGetSymbolAddress((void**)&gL,   HIP_SYMBOL(g_gL));

  dim3 ggrid(INNER / 64, BT / 64);
  dim3 gblk(256);

  sgemm_nt<<<ggrid, gblk, 0, stream>>>(x, wq, pre, BT, INNER, CC);
  conv_silu_norm<<<BT, 256, 0, stream>>>(pre, cqw, cqb, q, 1);
  sgemm_nt<<<ggrid, gblk, 0, stream>>>(x, wk, pre, BT, INNER, CC);
  conv_silu_norm<<<BT, 256, 0, stream>>>(pre, ckw, ckb, k, 1);
  sgemm_nt<<<ggrid, gblk, 0, stream>>>(x, wv, pre, BT, INNER, CC);
  conv_silu_norm<<<BT, 256, 0, stream>>>(pre, cvw, cvb, v, 0);
  sgemm_nt<<<ggrid, gblk, 0, stream>>>(x, wg, g, BT, INNER, CC);
  proj_ab<<<BT, 64, 0, stream>>>(x, wa, wb, dtb, A_log, beta, ldec);

  gdn_prep<<<NCHK, 256, 0, stream>>>(q, k, v, beta, ldec,
                                     U0, Wt, Bt, Qht, Kh, gL);
  gdn_seq<<<NBH, 256, 0, stream>>>(U0, Wt, Bt, Qht, Kh, gL, out);

  norm_gate<<<BT, 256, 0, stream>>>(out, g, oscale, pre);
  sgemm_nt<<<ggrid, gblk, 0, stream>>>(pre, wo, out, BT, CC, INNER);
}

// Round 3
// 1189.464 us; speedup vs baseline: 2.8917x; 1.0015x over previous
//
#include <hip/hip_runtime.h>
#include <math.h>

#define BB 2
#define TT 2048
#define CC 1024
#define HH 16
#define DD 64
#define INNER 1024
#define BT (BB*TT)   /* 4096 */
#define EPSF 1e-6f
#define CH 64
#define NC (TT/CH)        /* 32 */
#define NBH (BB*HH)       /* 32 */
#define NCHK (NBH*NC)     /* 1024 */

// Static device scratch (fully overwritten every call; deterministic).
__device__ float g_pre[BT * INNER];
__device__ float g_q[BT * INNER];
__device__ float g_k[BT * INNER];
__device__ float g_v[BT * INNER];
__device__ float g_g[BT * INNER];
__device__ float g_beta[BT * HH];
__device__ float g_ldec[BT * HH];
// per-chunk precomputed tensors
__device__ float g_U0[NCHK * CH * DD];
__device__ float g_Wt[NCHK * DD * CH];
__device__ float g_Bt[NCHK * CH * CH];
__device__ float g_Qht[NCHK * DD * CH];
__device__ float g_Kh[NCHK * CH * DD];
__device__ float g_gL[NCHK];

// ---------------------------------------------------------------------------
// C[m,n] = sum_k A[m,k] * B[n,k]   (both operands K-contiguous, "NT" GEMM)
// ---------------------------------------------------------------------------
__global__ __launch_bounds__(256) void sgemm_nt(const float* __restrict__ A,
                                                const float* __restrict__ Bm,
                                                float* __restrict__ Cm,
                                                int M, int N, int K) {
  __shared__ float As[16][64];
  __shared__ float Bs[16][64];
  const int tid = threadIdx.x;
  const int bm = blockIdx.y * 64;
  const int bn = blockIdx.x * 64;
  const int lr = tid >> 2;
  const int lk = (tid & 3) * 4;
  const int tx = tid & 15;
  const int ty = tid >> 4;
  float acc[4][4] = {};
  for (int k0 = 0; k0 < K; k0 += 16) {
    float4 av = *(const float4*)&A[(bm + lr) * K + k0 + lk];
    float4 bv = *(const float4*)&Bm[(bn + lr) * K + k0 + lk];
    __syncthreads();
    As[lk + 0][lr] = av.x; As[lk + 1][lr] = av.y;
    As[lk + 2][lr] = av.z; As[lk + 3][lr] = av.w;
    Bs[lk + 0][lr] = bv.x; Bs[lk + 1][lr] = bv.y;
    Bs[lk + 2][lr] = bv.z; Bs[lk + 3][lr] = bv.w;
    __syncthreads();
#pragma unroll
    for (int kk = 0; kk < 16; ++kk) {
      float4 a4 = *(const float4*)&As[kk][ty * 4];
      float4 b4 = *(const float4*)&Bs[kk][tx * 4];
      float ar[4] = {a4.x, a4.y, a4.z, a4.w};
      float br[4] = {b4.x, b4.y, b4.z, b4.w};
#pragma unroll
      for (int i = 0; i < 4; ++i)
#pragma unroll
        for (int j = 0; j < 4; ++j) acc[i][j] += ar[i] * br[j];
    }
  }
#pragma unroll
  for (int i = 0; i < 4; ++i) {
    int m = bm + ty * 4 + i;
    float4 r = make_float4(acc[i][0], acc[i][1], acc[i][2], acc[i][3]);
    *(float4*)&Cm[m * N + bn + tx * 4] = r;
  }
}

// ---------------------------------------------------------------------------
// Causal depthwise conv1d(K=4) + SiLU, optional per-head L2 norm over D=64.
// ---------------------------------------------------------------------------
__global__ __launch_bounds__(256) void conv_silu_norm(
    const float* __restrict__ pre, const float* __restrict__ cw,
    const float* __restrict__ cb, float* __restrict__ out, int do_l2) {
  const int bt = blockIdx.x;
  const int b = bt / TT, t = bt % TT;
  const int tid = threadIdx.x;
  const int c4 = tid * 4;
  float4 xt[4];
#pragma unroll
  for (int j = 0; j < 4; ++j) {
    int ts = t - 3 + j;
    xt[j] = (ts >= 0) ? *(const float4*)&pre[(b * TT + ts) * INNER + c4]
                      : make_float4(0.f, 0.f, 0.f, 0.f);
  }
  float4 bias4 = *(const float4*)&cb[c4];
  const float* bp = (const float*)&bias4;
  float y[4];
#pragma unroll
  for (int ci = 0; ci < 4; ++ci) {
    float4 w4 = *(const float4*)&cw[(c4 + ci) * 4];
    float acc = bp[ci];
    acc += w4.x * ((const float*)&xt[0])[ci];
    acc += w4.y * ((const float*)&xt[1])[ci];
    acc += w4.z * ((const float*)&xt[2])[ci];
    acc += w4.w * ((const float*)&xt[3])[ci];
    y[ci] = acc / (1.f + expf(-acc));   // SiLU
  }
  if (do_l2) {
    float ssq = y[0]*y[0] + y[1]*y[1] + y[2]*y[2] + y[3]*y[3];
    ssq += __shfl_xor(ssq, 1);
    ssq += __shfl_xor(ssq, 2);
    ssq += __shfl_xor(ssq, 4);
    ssq += __shfl_xor(ssq, 8);
    float r = rsqrtf(ssq + EPSF);
    y[0] *= r; y[1] *= r; y[2] *= r; y[3] *= r;
  }
  *(float4*)&out[bt * INNER + c4] = make_float4(y[0], y[1], y[2], y[3]);
}

// ---------------------------------------------------------------------------
// beta = sigmoid(x@wb.T); ldec = -exp(A_log)*softplus(x@wa.T + dt_bias)
// ---------------------------------------------------------------------------
__global__ __launch_bounds__(64) void proj_ab(
    const float* __restrict__ x, const float* __restrict__ wa,
    const float* __restrict__ wb, const float* __restrict__ dt_bias,
    const float* __restrict__ A_log, float* __restrict__ beta,
    float* __restrict__ ldec) {
  const int m = blockIdx.x;
  const int lane = threadIdx.x;
  const float* xr = &x[m * CC];
  if (lane < 16) {
    const float* wr = &wa[lane * CC];
    float acc = 0.f;
    for (int kk = 0; kk < CC; kk += 4) {
      float4 xv = *(const float4*)&xr[kk];
      float4 wv = *(const float4*)&wr[kk];
      acc += xv.x * wv.x + xv.y * wv.y + xv.z * wv.z + xv.w * wv.w;
    }
    float a = acc + dt_bias[lane];
    float sp = fmaxf(a, 0.f) + log1pf(expf(-fabsf(a)));  // softplus, stable
    ldec[m * HH + lane] = -expf(A_log[lane]) * sp;       // log of decay
  } else if (lane < 32) {
    const int hh = lane - 16;
    const float* wr = &wb[hh * CC];
    float acc = 0.f;
    for (int kk = 0; kk < CC; kk += 4) {
      float4 xv = *(const float4*)&xr[kk];
      float4 wv = *(const float4*)&wr[kk];
      acc += xv.x * wv.x + xv.y * wv.y + xv.z * wv.z + xv.w * wv.w;
    }
    beta[m * HH + hh] = 1.f / (1.f + expf(-acc));
  }
}

// ---------------------------------------------------------------------------
// Per-chunk parallel precompute for chunked delta rule.
// grid = NBH*NC blocks (1024), 256 threads.
// Produces U0, Wt (transposed), Bt (transposed), Qht (transposed), Kh, gL.
// ---------------------------------------------------------------------------
__global__ __launch_bounds__(256) void gdn_prep(
    const float* __restrict__ q, const float* __restrict__ k,
    const float* __restrict__ v, const float* __restrict__ beta,
    const float* __restrict__ ldec,
    float* __restrict__ U0g, float* __restrict__ Wtg, float* __restrict__ Btg,
    float* __restrict__ Qhtg, float* __restrict__ Khg, float* __restrict__ gLg) {
  const int blk = blockIdx.x;
  const int bh = blk / NC, c = blk % NC;
  const int b = bh >> 4, h = bh & 15;
  const int tid = threadIdx.x;
  const int tx = tid & 15, ty = tid >> 4;
  __shared__ float P0[64][68];   // kst[d][t] -> later U0[t][e]
  __shared__ float P1[64][68];   // qst[d][t] -> later W[t][d]
  __shared__ float Ab[64][65];   // A[t][s]
  __shared__ float lam[64], lamx[64], lbet[64];
  const long gb = ((long)(b * TT + c * CH) * HH + h) * DD;

  // stage k,q transposed
  {
    const int e4 = (tid & 15) * 4;
    const int t0 = tid >> 4;
#pragma unroll
    for (int p = 0; p < 4; ++p) {
      int t = t0 + p * 16;
      float4 kv = *(const float4*)&k[gb + (long)t * (HH * DD) + e4];
      float4 qv = *(const float4*)&q[gb + (long)t * (HH * DD) + e4];
      P0[e4 + 0][t] = kv.x; P0[e4 + 1][t] = kv.y;
      P0[e4 + 2][t] = kv.z; P0[e4 + 3][t] = kv.w;
      P1[e4 + 0][t] = qv.x; P1[e4 + 1][t] = qv.y;
      P1[e4 + 2][t] = qv.z; P1[e4 + 3][t] = qv.w;
    }
  }
  // lam (inclusive log-decay prefix), lamx (exclusive), lbet
  float ldv = 0.f, bv_ = 0.f;
  if (tid < 64) {
    ldv = ldec[(long)(b * TT + c * CH + tid) * HH + h];
    bv_ = beta[(long)(b * TT + c * CH + tid) * HH + h];
    lam[tid] = ldv;
  }
  __syncthreads();
  float lsum = 0.f;
  if (tid < 64) {
    for (int s = 0; s <= tid; ++s) lsum += lam[s];
  }
  __syncthreads();
  if (tid < 64) {
    lam[tid] = lsum;
    lamx[tid] = lsum - ldv;
    lbet[tid] = bv_;
  }
  __syncthreads();

  // G[r][c]=k_r.k_c ; Pm[r][c]=k_r.q_c  (both via transposed operands)
  float accg[4][4] = {}, accp[4][4] = {};
  for (int d = 0; d < 64; ++d) {
    float4 a4 = *(const float4*)&P0[d][ty * 4];
    float4 bk = *(const float4*)&P0[d][tx * 4];
    float4 bq = *(const float4*)&P1[d][tx * 4];
    float ar[4] = {a4.x, a4.y, a4.z, a4.w};
    float bkr[4] = {bk.x, bk.y, bk.z, bk.w};
    float bqr[4] = {bq.x, bq.y, bq.z, bq.w};
#pragma unroll
    for (int i = 0; i < 4; ++i)
#pragma unroll
      for (int j = 0; j < 4; ++j) {
        accg[i][j] += ar[i] * bkr[j];
        accp[i][j] += ar[i] * bqr[j];
      }
  }
  // A[t][s] = (s<t) beta_t exp(lamx_t - lam_s) k_t.k_s   (t=ty4+i rows of accg)
#pragma unroll
  for (int i = 0; i < 4; ++i) {
    int t = ty * 4 + i;
    float bt_ = lbet[t], lx = lamx[t];
#pragma unroll
    for (int j = 0; j < 4; ++j) {
      int s = tx * 4 + j;
      Ab[t][s] = (s < t) ? bt_ * expf(lx - lam[s]) * accg[i][j] : 0.f;
    }
  }
  // Bt[s][t] = (s<=t) exp(lam_t - lam_s) q_t.k_s   (s=ty4+i, t=tx4+j)
  {
    float* btp = Btg + (long)blk * (CH * CH);
#pragma unroll
    for (int i = 0; i < 4; ++i) {
      int s = ty * 4 + i;
      float ls = lam[s];
      int t0 = tx * 4;
      float4 w;
      w.x = (s <= t0 + 0) ? expf(lam[t0 + 0] - ls) * accp[i][0] : 0.f;
      w.y = (s <= t0 + 1) ? expf(lam[t0 + 1] - ls) * accp[i][1] : 0.f;
      w.z = (s <= t0 + 2) ? expf(lam[t0 + 2] - ls) * accp[i][2] : 0.f;
      w.w = (s <= t0 + 3) ? expf(lam[t0 + 3] - ls) * accp[i][3] : 0.f;
      *(float4*)&btp[s * 64 + t0] = w;
    }
  }
  // Qht[d][t] = exp(lam_t) q[t][d]  (from qst, before P1 is reused)
  {
    float* qhp = Qhtg + (long)blk * (DD * CH);
    const int t4 = (tid & 15) * 4;
    const int d0 = tid >> 4;
#pragma unroll
    for (int p = 0; p < 4; ++p) {
      int d = d0 + p * 16;
      float4 qv = *(const float4*)&P1[d][t4];
      qv.x *= expf(lam[t4 + 0]); qv.y *= expf(lam[t4 + 1]);
      qv.z *= expf(lam[t4 + 2]); qv.w *= expf(lam[t4 + 3]);
      *(float4*)&qhp[d * 64 + t4] = qv;
    }
  }
  __syncthreads();
  // re-init: P0[t][e] = beta_t v ; P1[t][d] = beta_t exp(lamx_t) k
  {
    const int e4 = (tid & 15) * 4;
    const int t0 = tid >> 4;
#pragma unroll
    for (int p = 0; p < 4; ++p) {
      int t = t0 + p * 16;
      float bt_ = lbet[t], cx = bt_ * expf(lamx[t]);
      float4 vv = *(const float4*)&v[gb + (long)t * (HH * DD) + e4];
      float4 kv = *(const float4*)&k[gb + (long)t * (HH * DD) + e4];
      vv.x *= bt_; vv.y *= bt_; vv.z *= bt_; vv.w *= bt_;
      kv.x *= cx; kv.y *= cx; kv.z *= cx; kv.w *= cx;
      *(float4*)&P0[t][e4] = vv;
      *(float4*)&P1[t][e4] = kv;
    }
  }
  __syncthreads();
  // forward substitution (right-looking): rows r>t -= A[r][t]*row t, both P0,P1
  {
    const int j4 = (tid & 31) * 4;  // 0..124 ; <64 -> P0 col, else P1 col
    const int rofs = tid >> 5;      // 0..7
    float* Pj = (j4 < 64) ? (&P0[0][0] + j4) : (&P1[0][0] + (j4 - 64));
    for (int t = 0; t < 63; ++t) {
      __syncthreads();
      float4 ut = *(const float4*)&Pj[t * 68];
      for (int r = t + 1 + rofs; r < 64; r += 8) {
        float a = Ab[r][t];
        float4 ur = *(const float4*)&Pj[r * 68];
        ur.x -= a * ut.x; ur.y -= a * ut.y;
        ur.z -= a * ut.z; ur.w -= a * ut.w;
        *(float4*)&Pj[r * 68] = ur;
      }
    }
  }
  __syncthreads();
  // write U0 (natural) and Wt (transposed)
  {
    float* u0p = U0g + (long)blk * (CH * DD);
    const int e4 = (tid & 15) * 4;
    const int t0 = tid >> 4;
#pragma unroll
    for (int p = 0; p < 4; ++p) {
      int t = t0 + p * 16;
      *(float4*)&u0p[t * 64 + e4] = *(const float4*)&P0[t][e4];
    }
    float* wtp = Wtg + (long)blk * (DD * CH);
    const int t = tid & 63;
    const int d0 = tid >> 6;  // 0..3
#pragma unroll
    for (int p = 0; p < 16; ++p) {
      int d = d0 + p * 4;
      wtp[d * 64 + t] = P1[t][d];
    }
  }
  // Kh[s][d] = exp(lamL - lam_s) k[s][d] ; gL
  {
    float* khp = Khg + (long)blk * (CH * DD);
    float lamL = lam[63];
    const int e4 = (tid & 15) * 4;
    const int t0 = tid >> 4;
#pragma unroll
    for (int p = 0; p < 4; ++p) {
      int t = t0 + p * 16;
      float cf = expf(lamL - lam[t]);
      float4 kv = *(const float4*)&k[gb + (long)t * (HH * DD) + e4];
      kv.x *= cf; kv.y *= cf; kv.z *= cf; kv.w *= cf;
      *(float4*)&khp[t * 64 + e4] = kv;
    }
    if (tid == 0) gLg[blk] = expf(lamL);
  }
}

// ---------------------------------------------------------------------------
// Sequential inter-chunk pass: per (b,h), 32 chunk steps of 64x64x64 matmuls.
// u = U0 - W.S ; o = B.u + Qh.S ; S = gL.S + Kh^T.u
// ---------------------------------------------------------------------------
__global__ __launch_bounds__(256) void gdn_seq(
    const float* __restrict__ U0g, const float* __restrict__ Wtg,
    const float* __restrict__ Btg, const float* __restrict__ Qhtg,
    const float* __restrict__ Khg, const float* __restrict__ gLg,
    float* __restrict__ o) {
  const int bh = blockIdx.x;
  const int b = bh >> 4, h = bh & 15;
  const int tid = threadIdx.x;
  const int tx = tid & 15, ty = tid >> 4;
  __shared__ float S[64][64];
  __shared__ float ub[64][64];
  __shared__ float op[64][64];
#pragma unroll
  for (int p = 0; p < 16; ++p) ((float*)S)[tid + p * 256] = 0.f;
  const int e4 = (tid & 15) * 4;
  const int t0s = tid >> 4;

  for (int c = 0; c < NC; ++c) {
    const long blk = (long)(bh * NC + c);
    const float* wt = Wtg + blk * (DD * CH);
    const float* u0 = U0g + blk * (CH * DD);
    const float* bt = Btg + blk * (CH * CH);
    const float* qh = Qhtg + blk * (DD * CH);
    const float* kh = Khg + blk * (CH * DD);
    __syncthreads();
    // stage Wt
#pragma unroll
    for (int p = 0; p < 4; ++p) {
      int t = t0s + p * 16;
      *(float4*)&op[t][e4] = *(const float4*)&wt[t * 64 + e4];
    }
    __syncthreads();
    // u = U0 - W.S
    float acc[4][4];
#pragma unroll
    for (int i = 0; i < 4; ++i) {
      float4 u4 = *(const float4*)&u0[(ty * 4 + i) * 64 + tx * 4];
      acc[i][0] = u4.x; acc[i][1] = u4.y; acc[i][2] = u4.z; acc[i][3] = u4.w;
    }
    for (int d = 0; d < 64; ++d) {
      float4 a4 = *(const float4*)&op[d][ty * 4];
      float4 b4 = *(const float4*)&S[d][tx * 4];
      float ar[4] = {a4.x, a4.y, a4.z, a4.w};
      float br[4] = {b4.x, b4.y, b4.z, b4.w};
#pragma unroll
      for (int i = 0; i < 4; ++i)
#pragma unroll
        for (int j = 0; j < 4; ++j) acc[i][j] -= ar[i] * br[j];
    }
#pragma unroll
    for (int i = 0; i < 4; ++i)
      *(float4*)&ub[ty * 4 + i][tx * 4] =
          make_float4(acc[i][0], acc[i][1], acc[i][2], acc[i][3]);
    __syncthreads();
    // stage Bt
#pragma unroll
    for (int p = 0; p < 4; ++p) {
      int t = t0s + p * 16;
      *(float4*)&op[t][e4] = *(const float4*)&bt[t * 64 + e4];
    }
    __syncthreads();
    // o part1 = B.u
    float acco[4][4] = {};
    for (int s = 0; s < 64; ++s) {
      float4 a4 = *(const float4*)&op[s][ty * 4];
      float4 b4 = *(const float4*)&ub[s][tx * 4];
      float ar[4] = {a4.x, a4.y, a4.z, a4.w};
      float br[4] = {b4.x, b4.y, b4.z, b4.w};
#pragma unroll
      for (int i = 0; i < 4; ++i)
#pragma unroll
        for (int j = 0; j < 4; ++j) acco[i][j] += ar[i] * br[j];
    }
    __syncthreads();
    // stage Qht
#pragma unroll
    for (int p = 0; p < 4; ++p) {
      int t = t0s + p * 16;
      *(float4*)&op[t][e4] = *(const float4*)&qh[t * 64 + e4];
    }
    __syncthreads();
    // o part2 += Qh.S ; write o
    for (int d = 0; d < 64; ++d) {
      float4 a4 = *(const float4*)&op[d][ty * 4];
      float4 b4 = *(const float4*)&S[d][tx * 4];
      float ar[4] = {a4.x, a4.y, a4.z, a4.w};
      float br[4] = {b4.x, b4.y, b4.z, b4.w};
#pragma unroll
      for (int i = 0; i < 4; ++i)
#pragma unroll
        for (int j = 0; j < 4; ++j) acco[i][j] += ar[i] * br[j];
    }
#pragma unroll
    for (int i = 0; i < 4; ++i) {
      int t = ty * 4 + i;
      *(float4*)&o[((long)(b * TT + c * CH + t) * HH + h) * DD + tx * 4] =
          make_float4(acco[i][0], acco[i][1], acco[i][2], acco[i][3]);
    }
    __syncthreads();
    // stage Kh
#pragma unroll
    for (int p = 0; p < 4; ++p) {
      int t = t0s + p * 16;
      *(float4*)&op[t][e4] = *(const float4*)&kh[t * 64 + e4];
    }
    __syncthreads();
    // S = gL*S + Kh^T.u   (rows d = ty4+i, cols e = tx4+j)
    float gL = gLg[blk];
    float accs[4][4];
#pragma unroll
    for (int i = 0; i < 4; ++i)
#pragma unroll
      for (int j = 0; j < 4; ++j) accs[i][j] = gL * S[ty * 4 + i][tx * 4 + j];
    for (int s = 0; s < 64; ++s) {
      float4 a4 = *(const float4*)&op[s][ty * 4];
      float4 b4 = *(const float4*)&ub[s][tx * 4];
      float ar[4] = {a4.x, a4.y, a4.z, a4.w};
      float br[4] = {b4.x, b4.y, b4.z, b4.w};
#pragma unroll
      for (int i = 0; i < 4; ++i)
#pragma unroll
        for (int j = 0; j < 4; ++j) accs[i][j] += ar[i] * br[j];
    }
#pragma unroll
    for (int i = 0; i < 4; ++i)
      *(float4*)&S[ty * 4 + i][tx * 4] =
          make_float4(accs[i][0], accs[i][1], accs[i][2], accs[i][3]);
  }
}

// ---------------------------------------------------------------------------
// o = rms_norm(o) * o_norm_scale * silu(g)
// ---------------------------------------------------------------------------
__global__ __launch_bounds__(256) void norm_gate(
    const float* __restrict__ o, const float* __restrict__ g,
    const float* __restrict__ scale, float* __restrict__ out) {
  const int bt = blockIdx.x;
  const int tid = threadIdx.x;
  const int c4 = tid * 4;
  float4 o4 = *(const float4*)&o[bt * INNER + c4];
  float ssq = o4.x * o4.x + o4.y * o4.y + o4.z * o4.z + o4.w * o4.w;
  ssq += __shfl_xor(ssq, 1);
  ssq += __shfl_xor(ssq, 2);
  ssq += __shfl_xor(ssq, 4);
  ssq += __shfl_xor(ssq, 8);
  float r = rsqrtf(ssq * (1.f / 64.f) + EPSF);
  float4 sc = *(const float4*)&scale[c4 & 63];
  float4 g4 = *(const float4*)&g[bt * INNER + c4];
  float4 res;
  res.x = o4.x * r * sc.x * (g4.x / (1.f + expf(-g4.x)));
  res.y = o4.y * r * sc.y * (g4.y / (1.f + expf(-g4.y)));
  res.z = o4.z * r * sc.z * (g4.z / (1.f + expf(-g4.z)));
  res.w = o4.w * r * sc.w * (g4.w / (1.f + expf(-g4.w)));
  *(float4*)&out[bt * INNER + c4] = res;
}

// ---------------------------------------------------------------------------
extern "C" void kernel_launch(void* const* d_in, const int* in_sizes, int n_in,
                              void* d_out, int out_size, void* d_ws,
                              size_t ws_size, hipStream_t stream) {
  const float* x      = (const float*)d_in[0];
  const float* wq     = (const float*)d_in[1];
  const float* wk     = (const float*)d_in[2];
  const float* wv     = (const float*)d_in[3];
  const float* wg     = (const float*)d_in[4];
  const float* wo     = (const float*)d_in[5];
  const float* wa     = (const float*)d_in[6];
  const float* wb     = (const float*)d_in[7];
  const float* cqw    = (const float*)d_in[8];
  const float* cqb    = (const float*)d_in[9];
  const float* ckw    = (const float*)d_in[10];
  const float* ckb    = (const float*)d_in[11];
  const float* cvw    = (const float*)d_in[12];
  const float* cvb    = (const float*)d_in[13];
  const float* A_log  = (const float*)d_in[14];
  const float* dtb    = (const float*)d_in[15];
  const float* oscale = (const float*)d_in[16];
  float* out = (float*)d_out;

  float *pre, *q, *k, *v, *g, *beta, *ldec;
  float *U0, *Wt, *Bt, *Qht, *Kh, *gL;
  hipGetSymbolAddress((void**)&pre,  HIP_SYMBOL(g_pre));
  hipGetSymbolAddress((void**)&q,    HIP_SYMBOL(g_q));
  hipGetSymbolAddress((void**)&k,    HIP_SYMBOL(g_k));
  hipGetSymbolAddress((void**)&v,    HIP_SYMBOL(g_v));
  hipGetSymbolAddress((void**)&g,    HIP_SYMBOL(g_g));
  hipGetSymbolAddress((void**)&beta, HIP_SYMBOL(g_beta));
  hipGetSymbolAddress((void**)&ldec, HIP_SYMBOL(g_ldec));
  hipGetSymbolAddress((void**)&U0,   HIP_SYMBOL(g_U0));
  hipGetSymbolAddress((void**)&Wt,   HIP_SYMBOL(g_Wt));
  hipGetSymbolAddress((void**)&Bt,   HIP_SYMBOL(g_Bt));
  hipGetSymbolAddress((void**)&Qht,  HIP_SYMBOL(g_Qht));
  hipGetSymbolAddress((void**)&Kh,   HIP_SYMBOL(g_Kh));
  hipGetSymbolAddress((void**)&gL,   HIP_SYMBOL(g_gL));

  dim3 ggrid(INNER / 64, BT / 64);
  dim3 gblk(256);

  sgemm_nt<<<ggrid, gblk, 0, stream>>>(x, wq, pre, BT, INNER, CC);
  conv_silu_norm<<<BT, 256, 0, stream>>>(pre, cqw, cqb, q, 1);
  sgemm_nt<<<ggrid, gblk, 0, stream>>>(x, wk, pre, BT, INNER, CC);
  conv_silu_norm<<<BT, 256, 0, stream>>>(pre, ckw, ckb, k, 1);
  sgemm_nt<<<ggrid, gblk, 0, stream>>>(x, wv, pre, BT, INNER, CC);
  conv_silu_norm<<<BT, 256, 0, stream>>>(pre, cvw, cvb, v, 0);
  sgemm_nt<<<ggrid, gblk, 0, stream>>>(x, wg, g, BT, INNER, CC);
  proj_ab<<<BT, 64, 0, stream>>>(x, wa, wb, dtb, A_log, beta, ldec);

  gdn_prep<<<NCHK, 256, 0, stream>>>(q, k, v, beta, ldec,
                                     U0, Wt, Bt, Qht, Kh, gL);
  gdn_seq<<<NBH, 256, 0, stream>>>(U0, Wt, Bt, Qht, Kh, gL, out);

  norm_gate<<<BT, 256, 0, stream>>>(out, g, oscale, pre);
  sgemm_nt<<<ggrid, gblk, 0, stream>>>(pre, wo, out, BT, CC, INNER);
}